// Round 1
// baseline (25467.641 us; speedup 1.0000x reference)
//
#include <hip/hip_runtime.h>
#include <stdint.h>

// Problem constants
#define VOCAB  50000
#define EMBD   256
#define HIDD   512
#define G4     2048   // 4*HID
#define NBAT   256
#define TSEQ   512

// ---- workspace layout (bytes, all 256-aligned) ----
#define O_P2    0ull            // P2[v][j*4+g] bf16 : VOCAB*G4*2      = 204,800,000
#define O_EMBT  204800000ull    // emb bf16 [V][E]   : VOCAB*EMBD*2    =  25,600,000
#define O_WIH   230400000ull    // W_ih bf16 [G4][E] :                  =   1,048,576
#define O_WHH   231448576ull    // W_hh bf16 [G4][H] :                  =   2,097,152
#define O_TOKT  233545728ull    // tokT int [2][T][N]:                  =   1,048,576
#define O_HBUF  234594304ull    // h bf16 [2 lstm][2 phase][N][H]       =   1,048,576
#define O_BAR   235642880ull    // 64 x u32 barrier counters
#define WS_NEED 235643136ull

typedef __bf16 bf16x8 __attribute__((ext_vector_type(8)));
typedef float  f32x4  __attribute__((ext_vector_type(4)));

__device__ __forceinline__ unsigned short f2bf(float x) {
  unsigned u = __float_as_uint(x);
  u = (u + 0x7fffu + ((u >> 16) & 1u)) >> 16;   // RNE
  return (unsigned short)u;
}
__device__ __forceinline__ float b2f(unsigned short b) {
  return __uint_as_float(((unsigned)b) << 16);
}
__device__ __forceinline__ float sigf(float x) {
  float e = __builtin_amdgcn_exp2f(-1.4426950408889634f * x);
  return __builtin_amdgcn_rcpf(1.0f + e);
}
__device__ __forceinline__ float tanhf_(float x) {
  float e = __builtin_amdgcn_exp2f(-2.8853900817779268f * x);
  return 2.0f * __builtin_amdgcn_rcpf(1.0f + e) - 1.0f;
}

// ------------------------------------------------------------------
// K1: prep — bf16 converts, token transpose, zero h/barriers
// ------------------------------------------------------------------
__global__ void k_prep(const float* __restrict__ emb, const float* __restrict__ wih,
                       const float* __restrict__ whh, const int* __restrict__ tok1,
                       const int* __restrict__ tok2, unsigned short* __restrict__ embT,
                       unsigned short* __restrict__ wihb, unsigned short* __restrict__ whhb,
                       int* __restrict__ tokT, unsigned* __restrict__ hz,
                       unsigned* __restrict__ bar)
{
  const int stride = gridDim.x * blockDim.x;
  const int id0 = blockIdx.x * blockDim.x + threadIdx.x;
  for (int i = id0; i < VOCAB * EMBD; i += stride) embT[i] = f2bf(emb[i]);
  for (int i = id0; i < G4 * EMBD; i += stride)    wihb[i] = f2bf(wih[i]);
  for (int i = id0; i < G4 * HIDD; i += stride)    whhb[i] = f2bf(whh[i]);
  for (int i = id0; i < 2 * TSEQ * NBAT; i += stride) {
    int l = i >> 17, t = (i >> 8) & 511, n = i & 255;
    tokT[i] = (l ? tok2 : tok1)[n * TSEQ + t];
  }
  for (int i = id0; i < 262144; i += stride) hz[i] = 0u;   // zero h buffers (1 MiB)
  for (int i = id0; i < 64; i += stride) bar[i] = 0u;
}

// ------------------------------------------------------------------
// K2: vocab projection  P2[v][j*4+g] = emb[v]·W_ih[g*512+j] + b_ih + b_hh
// no-LDS MFMA GEMM, M=50000 N=2048 K=256, frags straight from L2
// ------------------------------------------------------------------
__global__ __launch_bounds__(256) void
k_proj(const unsigned short* __restrict__ embT, const unsigned short* __restrict__ wihb,
       const float* __restrict__ bih, const float* __restrict__ bhh,
       unsigned short* __restrict__ P2)
{
  const int l  = threadIdx.x & 63;
  const int w  = threadIdx.x >> 6;
  const int n0 = blockIdx.x * 128 + (w & 1) * 64;
  const int m0 = blockIdx.y * 128 + (w >> 1) * 64;
  const int lq = l >> 4, lc = l & 15;

  f32x4 acc[4][4];
  #pragma unroll
  for (int a = 0; a < 4; ++a)
    #pragma unroll
    for (int b = 0; b < 4; ++b) acc[a][b] = (f32x4){0.f, 0.f, 0.f, 0.f};

  const uint8_t* eb = (const uint8_t*)embT;
  const uint8_t* wb = (const uint8_t*)wihb;
  #pragma unroll
  for (int ks = 0; ks < 8; ++ks) {
    const int koff = ks * 64 + lq * 16;
    bf16x8 a[4], b[4];
    #pragma unroll
    for (int mt = 0; mt < 4; ++mt) {
      int row = m0 + mt * 16 + lc; if (row >= VOCAB) row = VOCAB - 1;
      a[mt] = *(const bf16x8*)(eb + (size_t)row * 512 + koff);
    }
    #pragma unroll
    for (int nt = 0; nt < 4; ++nt) {
      int g = n0 + nt * 16 + lc;
      b[nt] = *(const bf16x8*)(wb + (size_t)g * 512 + koff);
    }
    #pragma unroll
    for (int mt = 0; mt < 4; ++mt)
      #pragma unroll
      for (int nt = 0; nt < 4; ++nt)
        acc[mt][nt] = __builtin_amdgcn_mfma_f32_16x16x32_bf16(a[mt], b[nt], acc[mt][nt], 0, 0, 0);
  }

  #pragma unroll
  for (int mt = 0; mt < 4; ++mt)
    #pragma unroll
    for (int r = 0; r < 4; ++r) {
      const int vrow = m0 + mt * 16 + lq * 4 + r;
      if (vrow < VOCAB) {
        #pragma unroll
        for (int nt = 0; nt < 4; ++nt) {
          const int gcol = n0 + nt * 16 + lc;
          float v = acc[mt][nt][r] + bih[gcol] + bhh[gcol];
          const int colp = ((gcol & 511) << 2) | (gcol >> 9);  // [j][g] permuted
          P2[(size_t)vrow * 2048 + colp] = f2bf(v);
        }
      }
    }
}

// ------------------------------------------------------------------
// K3: persistent LSTM scan. 512 blocks x 64 threads (1 wave), 2 blocks/CU.
// block = (lstm, 32-row batch slice mg, 16-col hidden slice jb).
// W_hh slice resident in LDS; c in registers (MFMA C-layout, lane-local
// gate quads); h double-buffered in global; per-(lstm,mg) 32-block barrier.
// ------------------------------------------------------------------
#define W_STRIDE 1040   // 512*2 + 16 pad (16B aligned, breaks bank conflicts)
#define XG_STRIDE 144   // 16*4*2 + 16 pad

__global__ __launch_bounds__(64) void
k_lstm(const uint8_t* __restrict__ P2, const int* __restrict__ tokT,
       const uint8_t* __restrict__ whh, uint8_t* __restrict__ hbuf,
       unsigned* __restrict__ bar)
{
  __shared__ __align__(16) uint8_t smem[64 * W_STRIDE + 32 * XG_STRIDE]; // 71,168 B
  uint8_t* Wlds = smem;
  uint8_t* xg   = smem + 64 * W_STRIDE;

  const int l    = threadIdx.x;
  const int bid  = blockIdx.x;
  const int jb   = bid & 31;
  const int mg   = (bid >> 5) & 7;
  const int lstm = bid >> 8;
  const int grp  = bid >> 5;       // 0..15, 32 blocks each
  const int m0   = mg * 32;
  const int j0   = jb * 16;
  const int lq   = l >> 4, lc = l & 15;

  // --- persistent: stage W_hh slice. LDS row n=g*16+jl <-> W_hh row g*512+j0+jl
  {
    const int g = l >> 4, jl = l & 15;
    const uint8_t* src = whh + (size_t)(g * 512 + j0 + jl) * 1024;
    uint8_t* dst = Wlds + l * W_STRIDE;
    #pragma unroll 8
    for (int c = 0; c < 64; ++c)
      *(uint4*)(dst + c * 16) = *(const uint4*)(src + c * 16);
  }
  __syncthreads();

  float cst[8];
  #pragma unroll
  for (int i = 0; i < 8; ++i) cst[i] = 0.0f;

  const size_t hslot = (size_t)NBAT * HIDD * 2;   // 262144 B

  for (int t = 0; t < TSEQ; ++t) {
    // ---- issue xg gather early (overlaps with K-loop) ----
    const int grow = l >> 1, ghalf = l & 1;
    const int tok = tokT[((lstm * TSEQ + t) << 8) + m0 + grow];
    const uint8_t* gsrc = P2 + (size_t)tok * 4096 + jb * 128 + ghalf * 64;
    uint4 q0 = *(const uint4*)(gsrc);
    uint4 q1 = *(const uint4*)(gsrc + 16);
    uint4 q2 = *(const uint4*)(gsrc + 32);
    uint4 q3 = *(const uint4*)(gsrc + 48);

    // ---- gates[m, g*16+jl] += h[m,:] . W_hh[g*512+j0+jl, :] ----
    const uint8_t* hprev = hbuf + (size_t)(lstm * 2 + (t & 1)) * hslot;
    f32x4 acc[2][4];
    #pragma unroll
    for (int mt = 0; mt < 2; ++mt)
      #pragma unroll
      for (int g = 0; g < 4; ++g) acc[mt][g] = (f32x4){0.f, 0.f, 0.f, 0.f};

    #pragma unroll
    for (int ks = 0; ks < 16; ++ks) {
      const int koff = ks * 64 + lq * 16;
      bf16x8 av[2], bv[4];
      av[0] = *(const bf16x8*)(hprev + (size_t)(m0 + lc) * 1024 + koff);
      av[1] = *(const bf16x8*)(hprev + (size_t)(m0 + 16 + lc) * 1024 + koff);
      #pragma unroll
      for (int g = 0; g < 4; ++g)
        bv[g] = *(const bf16x8*)(Wlds + (g * 16 + lc) * W_STRIDE + koff);
      #pragma unroll
      for (int mt = 0; mt < 2; ++mt)
        #pragma unroll
        for (int g = 0; g < 4; ++g)
          acc[mt][g] = __builtin_amdgcn_mfma_f32_16x16x32_bf16(av[mt], bv[g], acc[mt][g], 0, 0, 0);
    }

    // park gathered xg rows in LDS: xg[row][jl][g] bf16
    {
      uint8_t* dst = xg + grow * XG_STRIDE + ghalf * 64;
      *(uint4*)(dst)      = q0;
      *(uint4*)(dst + 16) = q1;
      *(uint4*)(dst + 32) = q2;
      *(uint4*)(dst + 48) = q3;
    }
    __syncthreads();

    // ---- epilogue: all 4 gates of a cell are lane-local ----
    uint8_t* hnext = hbuf + (size_t)(lstm * 2 + ((t + 1) & 1)) * hslot;
    #pragma unroll
    for (int mt = 0; mt < 2; ++mt) {
      #pragma unroll
      for (int r = 0; r < 4; ++r) {
        const int rrow = mt * 16 + lq * 4 + r;   // C-layout row
        ushort4 xq = *(const ushort4*)(xg + rrow * XG_STRIDE + lc * 8);
        float pi = acc[mt][0][r] + b2f(xq.x);
        float pf = acc[mt][1][r] + b2f(xq.y);
        float pg = acc[mt][2][r] + b2f(xq.z);
        float po = acc[mt][3][r] + b2f(xq.w);
        float iv = sigf(pi), fv = sigf(pf), gv = tanhf_(pg), ov = sigf(po);
        const int ci = mt * 4 + r;
        float cv = fv * cst[ci] + iv * gv; cst[ci] = cv;
        float hv = ov * tanhf_(cv);
        *(unsigned short*)(hnext + (size_t)(m0 + rrow) * 1024 + (j0 + lc) * 2) = f2bf(hv);
      }
    }
    __syncthreads();   // WAR guard on xg LDS before next step's writes

    // ---- inter-block group barrier (release h writes / acquire peers') ----
    if (t != TSEQ - 1) {
      __threadfence();                         // release: drain + writeback
      if (l == 0) {
        __hip_atomic_fetch_add(bar + grp, 1u, __ATOMIC_RELAXED, __HIP_MEMORY_SCOPE_AGENT);
        const unsigned tgt = 32u * (unsigned)(t + 1);
        int guard = 0;
        while (__hip_atomic_load(bar + grp, __ATOMIC_RELAXED, __HIP_MEMORY_SCOPE_AGENT) < tgt) {
          __builtin_amdgcn_s_sleep(1);
          if (++guard > 30000) break;          // fail visible, not hung
        }
      }
      __threadfence();                         // acquire: invalidate stale
    }
  }
}

// ------------------------------------------------------------------
// K4: h1*h2 -> logits -> softmax. one wave per batch row.
// ------------------------------------------------------------------
__global__ __launch_bounds__(64) void
k_fc(const uint8_t* __restrict__ hbuf, const float* __restrict__ wfc,
     const float* __restrict__ bfc, float* __restrict__ out)
{
  const int n = blockIdx.x, l = threadIdx.x;
  const unsigned short* h1 = (const unsigned short*)(hbuf) + (size_t)n * HIDD;                // lstm0 phase0
  const unsigned short* h2 = (const unsigned short*)(hbuf + 2 * (size_t)NBAT * HIDD * 2) + (size_t)n * HIDD; // lstm1 phase0
  float s0 = 0.f, s1 = 0.f;
  for (int j = l; j < HIDD; j += 64) {
    float hv = b2f(h1[j]) * b2f(h2[j]);
    s0 += hv * wfc[j];
    s1 += hv * wfc[HIDD + j];
  }
  #pragma unroll
  for (int off = 32; off > 0; off >>= 1) {
    s0 += __shfl_down(s0, off, 64);
    s1 += __shfl_down(s1, off, 64);
  }
  if (l == 0) {
    s0 += bfc[0]; s1 += bfc[1];
    float m  = fmaxf(s0, s1);
    float e0 = __builtin_amdgcn_exp2f((s0 - m) * 1.4426950408889634f);
    float e1 = __builtin_amdgcn_exp2f((s1 - m) * 1.4426950408889634f);
    float inv = 1.0f / (e0 + e1);
    out[n * 2 + 0] = e0 * inv;
    out[n * 2 + 1] = e1 * inv;
  }
}

// ------------------------------------------------------------------
extern "C" void kernel_launch(void* const* d_in, const int* in_sizes, int n_in,
                              void* d_out, int out_size, void* d_ws, size_t ws_size,
                              hipStream_t stream) {
  (void)in_sizes; (void)n_in; (void)out_size;
  if (ws_size < WS_NEED) return;   // fail visibly (absmax) rather than scribble OOB

  const int*   tok1 = (const int*)d_in[0];
  const int*   tok2 = (const int*)d_in[1];
  const float* emb  = (const float*)d_in[2];
  const float* wih  = (const float*)d_in[3];
  const float* whh  = (const float*)d_in[4];
  const float* bih  = (const float*)d_in[5];
  const float* bhh  = (const float*)d_in[6];
  const float* wfc  = (const float*)d_in[7];
  const float* bfc  = (const float*)d_in[8];
  float* out = (float*)d_out;

  uint8_t* ws = (uint8_t*)d_ws;
  unsigned short* P2   = (unsigned short*)(ws + O_P2);
  unsigned short* embT = (unsigned short*)(ws + O_EMBT);
  unsigned short* wihb = (unsigned short*)(ws + O_WIH);
  unsigned short* whhb = (unsigned short*)(ws + O_WHH);
  int*            tokT = (int*)(ws + O_TOKT);
  uint8_t*        hbuf = ws + O_HBUF;
  unsigned*       bar  = (unsigned*)(ws + O_BAR);

  k_prep<<<1024, 256, 0, stream>>>(emb, wih, whh, tok1, tok2, embT, wihb, whhb,
                                   tokT, (unsigned*)hbuf, bar);
  k_proj<<<dim3(16, 391), 256, 0, stream>>>(embT, wihb, bih, bhh, P2);

  {
    const uint8_t* p2p = (const uint8_t*)P2;
    const int*     tkp = tokT;
    const uint8_t* whp = (const uint8_t*)whhb;
    uint8_t*       hbp = hbuf;
    unsigned*      brp = bar;
    void* args[5] = {(void*)&p2p, (void*)&tkp, (void*)&whp, (void*)&hbp, (void*)&brp};
    hipError_t e = hipLaunchCooperativeKernel((void*)k_lstm, dim3(512), dim3(64),
                                              args, 0, stream);
    if (e != hipSuccess) {
      (void)hipGetLastError();  // clear; fall back to normal launch (de-facto co-resident)
      k_lstm<<<512, 64, 0, stream>>>(p2p, tkp, whp, hbp, brp);
    }
  }

  k_fc<<<256, 64, 0, stream>>>(hbuf, wfc, bfc, out);
}

// Round 3
// 6342.601 us; speedup vs baseline: 4.0153x; 4.0153x over previous
//
#include <hip/hip_runtime.h>
#include <stdint.h>

// Problem constants
#define VOCAB  50000
#define EMBD   256
#define HIDD   512
#define G4     2048   // 4*HID
#define NBAT   256
#define TSEQ   512

// ---- workspace layout (bytes) ----
#define O_P2    0ull            // P2[v][j*4+g] bf16 : VOCAB*G4*2      = 204,800,000
#define O_EMBT  204800000ull    // emb bf16 [V][E]
#define O_WIH   230400000ull    // W_ih bf16 [G4][E]
#define O_WHH   231448576ull    // W_hh bf16 [G4][H]
#define O_TOKT  233545728ull    // tokT int [2][T][N]
#define O_HBUF  234594304ull    // h bf16 [2 lstm][2 phase][N][H] = 1 MiB
#define O_BAR   235642880ull    // 16 u32 group counters (64 u32 zeroed)
#define WS_NEED 235643136ull

typedef __bf16 bf16x8 __attribute__((ext_vector_type(8)));
typedef float  f32x4  __attribute__((ext_vector_type(4)));
typedef float  f32x16 __attribute__((ext_vector_type(16)));

__device__ __forceinline__ unsigned short f2bf(float x) {
  unsigned u = __float_as_uint(x);
  u = (u + 0x7fffu + ((u >> 16) & 1u)) >> 16;   // RNE
  return (unsigned short)u;
}
__device__ __forceinline__ float b2f(unsigned short b) {
  return __uint_as_float(((unsigned)b) << 16);
}
__device__ __forceinline__ float sigf(float x) {
  float e = __builtin_amdgcn_exp2f(-1.4426950408889634f * x);
  return __builtin_amdgcn_rcpf(1.0f + e);
}
__device__ __forceinline__ float tanhf_(float x) {
  float e = __builtin_amdgcn_exp2f(-2.8853900817779268f * x);
  return 2.0f * __builtin_amdgcn_rcpf(1.0f + e) - 1.0f;
}

// ------------------------------------------------------------------
// K1: prep — bf16 converts, token transpose, zero h/counters
// ------------------------------------------------------------------
__global__ void k_prep(const float* __restrict__ emb, const float* __restrict__ wih,
                       const float* __restrict__ whh, const int* __restrict__ tok1,
                       const int* __restrict__ tok2, unsigned short* __restrict__ embT,
                       unsigned short* __restrict__ wihb, unsigned short* __restrict__ whhb,
                       int* __restrict__ tokT, unsigned* __restrict__ hz,
                       unsigned* __restrict__ bar)
{
  const int stride = gridDim.x * blockDim.x;
  const int id0 = blockIdx.x * blockDim.x + threadIdx.x;
  for (int i = id0; i < VOCAB * EMBD; i += stride) embT[i] = f2bf(emb[i]);
  for (int i = id0; i < G4 * EMBD; i += stride)    wihb[i] = f2bf(wih[i]);
  for (int i = id0; i < G4 * HIDD; i += stride)    whhb[i] = f2bf(whh[i]);
  for (int i = id0; i < 2 * TSEQ * NBAT; i += stride) {
    int l = i >> 17, t = (i >> 8) & 511, n = i & 255;
    tokT[i] = (l ? tok2 : tok1)[n * TSEQ + t];
  }
  for (int i = id0; i < 262144; i += stride) hz[i] = 0u;   // zero h buffers (1 MiB)
  for (int i = id0; i < 64; i += stride) bar[i] = 0u;      // group counters
}

// ------------------------------------------------------------------
// K2: vocab projection  P2[v][j*4+g] = emb[v]·W_ih[g*512+j] + b_ih + b_hh
// (unchanged — round-1 correctness-verified)
// ------------------------------------------------------------------
__global__ __launch_bounds__(256) void
k_proj(const unsigned short* __restrict__ embT, const unsigned short* __restrict__ wihb,
       const float* __restrict__ bih, const float* __restrict__ bhh,
       unsigned short* __restrict__ P2)
{
  const int l  = threadIdx.x & 63;
  const int w  = threadIdx.x >> 6;
  const int n0 = blockIdx.x * 128 + (w & 1) * 64;
  const int m0 = blockIdx.y * 128 + (w >> 1) * 64;
  const int lq = l >> 4, lc = l & 15;

  f32x4 acc[4][4];
  #pragma unroll
  for (int a = 0; a < 4; ++a)
    #pragma unroll
    for (int b = 0; b < 4; ++b) acc[a][b] = (f32x4){0.f, 0.f, 0.f, 0.f};

  const uint8_t* eb = (const uint8_t*)embT;
  const uint8_t* wb = (const uint8_t*)wihb;
  #pragma unroll
  for (int ks = 0; ks < 8; ++ks) {
    const int koff = ks * 64 + lq * 16;
    bf16x8 a[4], b[4];
    #pragma unroll
    for (int mt = 0; mt < 4; ++mt) {
      int row = m0 + mt * 16 + lc; if (row >= VOCAB) row = VOCAB - 1;
      a[mt] = *(const bf16x8*)(eb + (size_t)row * 512 + koff);
    }
    #pragma unroll
    for (int nt = 0; nt < 4; ++nt) {
      int g = n0 + nt * 16 + lc;
      b[nt] = *(const bf16x8*)(wb + (size_t)g * 512 + koff);
    }
    #pragma unroll
    for (int mt = 0; mt < 4; ++mt)
      #pragma unroll
      for (int nt = 0; nt < 4; ++nt)
        acc[mt][nt] = __builtin_amdgcn_mfma_f32_16x16x32_bf16(a[mt], b[nt], acc[mt][nt], 0, 0, 0);
  }

  #pragma unroll
  for (int mt = 0; mt < 4; ++mt)
    #pragma unroll
    for (int r = 0; r < 4; ++r) {
      const int vrow = m0 + mt * 16 + lq * 4 + r;
      if (vrow < VOCAB) {
        #pragma unroll
        for (int nt = 0; nt < 4; ++nt) {
          const int gcol = n0 + nt * 16 + lc;
          float v = acc[mt][nt][r] + bih[gcol] + bhh[gcol];
          const int colp = ((gcol & 511) << 2) | (gcol >> 9);  // [j][g] permuted
          P2[(size_t)vrow * 2048 + colp] = f2bf(v);
        }
      }
    }
}

// ------------------------------------------------------------------
// K3: persistent LSTM scan. 256 blocks x 256 threads (4 waves).
// block = (lstm, mg: 32 batch rows, jb: 32 hidden cols). wave = gate.
// W_hh slice (128KB) + h tile (32KB, xor-swizzled, reused as f32 gate
// buffer) = 160KB LDS. h + counters exchanged via RELAXED AGENT-scope
// atomics (compiler emits coherence-point encodings; NO wbl2/inv).
// Ordering: __syncthreads() drains vmcnt before the counter bump.
// ------------------------------------------------------------------
#define HL 131072   // LDS offset of h / gate-exchange region

__global__ __launch_bounds__(256, 1) void
k_lstm(const uint8_t* __restrict__ P2, const int* __restrict__ tokT,
       const uint8_t* __restrict__ whh, uint8_t* __restrict__ hbuf,
       unsigned* __restrict__ cnt)
{
  __shared__ __align__(16) uint8_t smem[163840];
  const int tid  = threadIdx.x;
  const int l    = tid & 63;
  const int w    = tid >> 6;        // wave = gate index
  const int bid  = blockIdx.x;
  const int jb   = bid & 15;
  const int mg   = (bid >> 4) & 7;
  const int lstm = bid >> 7;
  const int grp  = bid >> 4;        // 0..15, 16 blocks each (lstm, mg)
  const int m0   = mg * 32;
  const int j0   = jb * 32;

  // ---- stage W_hh gate-slice into LDS once, xor-swizzled ----
  // LDS row R = g*32 + jl  <->  W_hh row g*512 + j0 + jl ; 16B chunk c at (c ^ (R&7))
  for (int i = 0; i < 32; ++i) {
    const int G = i * 256 + tid;            // chunk id 0..8191
    const int R = G >> 6, c = G & 63;
    const uint8_t* src = whh + (size_t)((R >> 5) * 512 + j0 + (R & 31)) * 1024 + (size_t)c * 16;
    const uint4 v = *(const uint4*)src;
    *(uint4*)(smem + (size_t)R * 1024 + ((c ^ (R & 7)) * 16)) = v;
  }

  const size_t hslot = (size_t)NBAT * HIDD * 2;   // 262144 B
  const int em   = tid >> 3;        // epilogue batch row 0..31
  const int ecol = tid & 7;         // epilogue col group (4 cols)
  const int an   = l & 31;          // MFMA A-row / B-col (lane&31)
  const int ah   = l >> 5;          // k-half (lane>>5)
  const int Rrow = w * 32 + an;     // B LDS row

  float cst[4] = {0.f, 0.f, 0.f, 0.f};
  int tok_next = tokT[(lstm * TSEQ + 0) * NBAT + m0 + em];

  for (int t = 0; t < TSEQ; ++t) {
    // ---- wait for peer blocks to finish step t-1 (group counter, MALL) ----
    if (t > 0 && tid == 0) {
      const unsigned tgt = 16u * (unsigned)t;
      int guard = 0;
      while (__hip_atomic_load(cnt + grp, __ATOMIC_RELAXED, __HIP_MEMORY_SCOPE_AGENT) < tgt) {
        __builtin_amdgcn_s_sleep(2);
        if (++guard > 30000) break;            // fail visible, not hung
      }
    }
    __syncthreads();   // all waves past poll; LDS h region free (epilogue reads done)

    const int tok_cur = tok_next;

    // ---- issue xg gather + next-token load first (longest latency) ----
    const uint8_t* xsrc = P2 + (size_t)tok_cur * 4096 + (size_t)j0 * 8 + (size_t)ecol * 32;
    const uint4 xq0 = *(const uint4*)(xsrc);
    const uint4 xq1 = *(const uint4*)(xsrc + 16);
    if (t + 1 < TSEQ) tok_next = tokT[(lstm * TSEQ + (t + 1)) * NBAT + m0 + em];

    // ---- stage h tile (32 rows x 1KB) via agent-scope atomic loads ----
    {
      const uint8_t* hb = hbuf + (size_t)(lstm * 2 + (t & 1)) * hslot
                        + (size_t)m0 * 1024 + (size_t)tid * 8;
      unsigned long long v[16];
      #pragma unroll
      for (int i = 0; i < 16; ++i)
        v[i] = __hip_atomic_load((const unsigned long long*)(hb + (size_t)i * 2048),
                                 __ATOMIC_RELAXED, __HIP_MEMORY_SCOPE_AGENT);
      #pragma unroll
      for (int i = 0; i < 16; ++i) {
        const int m = i * 2 + (tid >> 7);
        const int c = (tid >> 1) & 63;
        const int half = tid & 1;
        *(unsigned long long*)(smem + HL + (size_t)m * 1024
                               + ((c ^ (m & 7)) * 16) + half * 8) = v[i];
      }
    }
    __syncthreads();   // h LDS ready (W was ready since before t-loop)

    // ---- GEMM: gate_w[32x32] = h[32x512] . W_g[32x512]^T (32x32x16 MFMA) ----
    f32x16 acc0{}, acc1{};
    #pragma unroll 8
    for (int ks = 0; ks < 32; ++ks) {
      const int ch = ks * 2 + ah;
      const bf16x8 av = *(const bf16x8*)(smem + HL + (size_t)an * 1024 + ((ch ^ (an & 7)) * 16));
      const bf16x8 bv = *(const bf16x8*)(smem + (size_t)Rrow * 1024 + ((ch ^ (an & 7)) * 16));
      if (ks & 1) acc1 = __builtin_amdgcn_mfma_f32_32x32x16_bf16(av, bv, acc1, 0, 0, 0);
      else        acc0 = __builtin_amdgcn_mfma_f32_32x32x16_bf16(av, bv, acc0, 0, 0, 0);
    }
    __syncthreads();   // A reads done; h region reusable as f32 gate buffer

    {
      float* gb = (float*)(smem + HL);   // gbuf[g][row 0..31][col 0..31] f32
      #pragma unroll
      for (int r = 0; r < 16; ++r) {
        const int row = (r & 3) + 8 * (r >> 2) + 4 * ah;   // 32x32 C/D mapping
        gb[w * 1024 + row * 32 + an] = acc0[r] + acc1[r];
      }
    }
    __syncthreads();   // gate buffer ready

    // ---- epilogue: 4 cells/lane, lane-local nonlinearity, h -> coherence pt ----
    {
      const float* gb = (const float*)(smem + HL);
      const f32x4 pi = *(const f32x4*)(gb + 0 * 1024 + em * 32 + ecol * 4);
      const f32x4 pf = *(const f32x4*)(gb + 1 * 1024 + em * 32 + ecol * 4);
      const f32x4 pg = *(const f32x4*)(gb + 2 * 1024 + em * 32 + ecol * 4);
      const f32x4 po = *(const f32x4*)(gb + 3 * 1024 + em * 32 + ecol * 4);
      unsigned short xsv[16];
      *(uint4*)(xsv) = xq0;
      *(uint4*)(xsv + 8) = xq1;
      unsigned short hv[4];
      #pragma unroll
      for (int k = 0; k < 4; ++k) {
        const float iv = sigf(pi[k] + b2f(xsv[k * 4 + 0]));
        const float fv = sigf(pf[k] + b2f(xsv[k * 4 + 1]));
        const float gv = tanhf_(pg[k] + b2f(xsv[k * 4 + 2]));
        const float ov = sigf(po[k] + b2f(xsv[k * 4 + 3]));
        const float cv = fv * cst[k] + iv * gv;
        cst[k] = cv;
        hv[k] = f2bf(ov * tanhf_(cv));
      }
      unsigned long long hp =
          (unsigned long long)hv[0] | ((unsigned long long)hv[1] << 16) |
          ((unsigned long long)hv[2] << 32) | ((unsigned long long)hv[3] << 48);
      uint8_t* hdst = hbuf + (size_t)(lstm * 2 + ((t + 1) & 1)) * hslot
                    + (size_t)(m0 + em) * 1024 + (size_t)(j0 + ecol * 4) * 2;
      __hip_atomic_store((unsigned long long*)hdst, hp,
                         __ATOMIC_RELAXED, __HIP_MEMORY_SCOPE_AGENT);
    }
    __syncthreads();   // barrier drain (s_waitcnt vmcnt(0)) => h at coherence point

    if (tid == 0 && t + 1 < TSEQ)
      __hip_atomic_fetch_add(cnt + grp, 1u, __ATOMIC_RELAXED, __HIP_MEMORY_SCOPE_AGENT);
  }
}

// ------------------------------------------------------------------
// K4: h1*h2 -> logits -> softmax. one wave per batch row.
// ------------------------------------------------------------------
__global__ __launch_bounds__(64) void
k_fc(const uint8_t* __restrict__ hbuf, const float* __restrict__ wfc,
     const float* __restrict__ bfc, float* __restrict__ out)
{
  const int n = blockIdx.x, l = threadIdx.x;
  const unsigned short* h1 = (const unsigned short*)(hbuf) + (size_t)n * HIDD;
  const unsigned short* h2 = (const unsigned short*)(hbuf + 2 * (size_t)NBAT * HIDD * 2) + (size_t)n * HIDD;
  float s0 = 0.f, s1 = 0.f;
  for (int j = l; j < HIDD; j += 64) {
    float hv = b2f(h1[j]) * b2f(h2[j]);
    s0 += hv * wfc[j];
    s1 += hv * wfc[HIDD + j];
  }
  #pragma unroll
  for (int off = 32; off > 0; off >>= 1) {
    s0 += __shfl_down(s0, off, 64);
    s1 += __shfl_down(s1, off, 64);
  }
  if (l == 0) {
    s0 += bfc[0]; s1 += bfc[1];
    float m  = fmaxf(s0, s1);
    float e0 = __builtin_amdgcn_exp2f((s0 - m) * 1.4426950408889634f);
    float e1 = __builtin_amdgcn_exp2f((s1 - m) * 1.4426950408889634f);
    float inv = 1.0f / (e0 + e1);
    out[n * 2 + 0] = e0 * inv;
    out[n * 2 + 1] = e1 * inv;
  }
}

// ------------------------------------------------------------------
extern "C" void kernel_launch(void* const* d_in, const int* in_sizes, int n_in,
                              void* d_out, int out_size, void* d_ws, size_t ws_size,
                              hipStream_t stream) {
  (void)in_sizes; (void)n_in; (void)out_size;
  if (ws_size < WS_NEED) return;   // fail visibly rather than scribble OOB

  const int*   tok1 = (const int*)d_in[0];
  const int*   tok2 = (const int*)d_in[1];
  const float* emb  = (const float*)d_in[2];
  const float* wih  = (const float*)d_in[3];
  const float* whh  = (const float*)d_in[4];
  const float* bih  = (const float*)d_in[5];
  const float* bhh  = (const float*)d_in[6];
  const float* wfc  = (const float*)d_in[7];
  const float* bfc  = (const float*)d_in[8];
  float* out = (float*)d_out;

  uint8_t* ws = (uint8_t*)d_ws;
  unsigned short* P2   = (unsigned short*)(ws + O_P2);
  unsigned short* embT = (unsigned short*)(ws + O_EMBT);
  unsigned short* wihb = (unsigned short*)(ws + O_WIH);
  unsigned short* whhb = (unsigned short*)(ws + O_WHH);
  int*            tokT = (int*)(ws + O_TOKT);
  uint8_t*        hbuf = ws + O_HBUF;
  unsigned*       cnt  = (unsigned*)(ws + O_BAR);

  k_prep<<<1024, 256, 0, stream>>>(emb, wih, whh, tok1, tok2, embT, wihb, whhb,
                                   tokT, (unsigned*)hbuf, cnt);
  k_proj<<<dim3(16, 391), 256, 0, stream>>>(embT, wihb, bih, bhh, P2);

  {
    const uint8_t* p2p = (const uint8_t*)P2;
    const int*     tkp = tokT;
    const uint8_t* whp = (const uint8_t*)whhb;
    uint8_t*       hbp = hbuf;
    unsigned*      cnp = cnt;
    void* args[5] = {(void*)&p2p, (void*)&tkp, (void*)&whp, (void*)&hbp, (void*)&cnp};
    hipError_t e = hipLaunchCooperativeKernel((void*)k_lstm, dim3(256), dim3(256),
                                              args, 0, stream);
    if (e != hipSuccess) {
      (void)hipGetLastError();  // clear; fall back (256 blocks @ 1/CU are co-resident)
      k_lstm<<<256, 256, 0, stream>>>(p2p, tkp, whp, hbp, cnp);
    }
  }

  k_fc<<<256, 64, 0, stream>>>(hbuf, wfc, bfc, out);
}

// Round 4
// 2249.202 us; speedup vs baseline: 11.3230x; 2.8199x over previous
//
#include <hip/hip_runtime.h>
#include <stdint.h>

// Problem constants
#define VOCAB  50000
#define EMBD   256
#define HIDD   512
#define G4     2048   // 4*HID
#define NBAT   256
#define TSEQ   512

// ---- workspace layout (bytes) ----
#define O_P2    0ull            // P2[v][j*4+g] bf16 : VOCAB*G4*2      = 204,800,000
#define O_EMBT  204800000ull    // emb bf16 [V][E] (dead after k_proj; flags live here)
#define O_WIH   230400000ull    // W_ih bf16 [G4][E]
#define O_WHH   231448576ull    // W_hh bf16 [G4][H]
#define O_TOKT  233545728ull    // tokT int [2][T][N]
#define O_HBUF  234594304ull    // h bf16 [2 lstm][2 phase][N][H] = 1 MiB
#define O_BAR   235642880ull    // (legacy, unused)
#define WS_NEED 235643136ull
#define O_FLAGS O_EMBT          // 256 flags x 256B stride = 64 KB, zeroed post-k_proj

typedef __bf16 bf16x8 __attribute__((ext_vector_type(8)));
typedef float  f32x4  __attribute__((ext_vector_type(4)));
typedef float  f32x16 __attribute__((ext_vector_type(16)));

__device__ __forceinline__ unsigned short f2bf(float x) {
  unsigned u = __float_as_uint(x);
  u = (u + 0x7fffu + ((u >> 16) & 1u)) >> 16;   // RNE
  return (unsigned short)u;
}
__device__ __forceinline__ float b2f(unsigned short b) {
  return __uint_as_float(((unsigned)b) << 16);
}
__device__ __forceinline__ float sigf(float x) {
  float e = __builtin_amdgcn_exp2f(-1.4426950408889634f * x);
  return __builtin_amdgcn_rcpf(1.0f + e);
}
__device__ __forceinline__ float tanhf_(float x) {
  float e = __builtin_amdgcn_exp2f(-2.8853900817779268f * x);
  return 2.0f * __builtin_amdgcn_rcpf(1.0f + e) - 1.0f;
}

// ------------------------------------------------------------------
// K1: prep — bf16 converts, token transpose, zero h
// ------------------------------------------------------------------
__global__ void k_prep(const float* __restrict__ emb, const float* __restrict__ wih,
                       const float* __restrict__ whh, const int* __restrict__ tok1,
                       const int* __restrict__ tok2, unsigned short* __restrict__ embT,
                       unsigned short* __restrict__ wihb, unsigned short* __restrict__ whhb,
                       int* __restrict__ tokT, unsigned* __restrict__ hz)
{
  const int stride = gridDim.x * blockDim.x;
  const int id0 = blockIdx.x * blockDim.x + threadIdx.x;
  for (int i = id0; i < VOCAB * EMBD; i += stride) embT[i] = f2bf(emb[i]);
  for (int i = id0; i < G4 * EMBD; i += stride)    wihb[i] = f2bf(wih[i]);
  for (int i = id0; i < G4 * HIDD; i += stride)    whhb[i] = f2bf(whh[i]);
  for (int i = id0; i < 2 * TSEQ * NBAT; i += stride) {
    int l = i >> 17, t = (i >> 8) & 511, n = i & 255;
    tokT[i] = (l ? tok2 : tok1)[n * TSEQ + t];
  }
  for (int i = id0; i < 262144; i += stride) hz[i] = 0u;   // zero h buffers (1 MiB)
}

// ------------------------------------------------------------------
// K1b: zero progress flags (runs after k_proj; flags overlap embT region)
// ------------------------------------------------------------------
__global__ void k_zero(unsigned* __restrict__ flags)
{
  const int i = blockIdx.x * blockDim.x + threadIdx.x;
  if (i < 16384) flags[i] = 0u;   // 64 KB
}

// ------------------------------------------------------------------
// K2: vocab projection  P2[v][j*4+g] = emb[v]·W_ih[g*512+j] + b_ih + b_hh
// (unchanged — round-1 correctness-verified)
// ------------------------------------------------------------------
__global__ __launch_bounds__(256) void
k_proj(const unsigned short* __restrict__ embT, const unsigned short* __restrict__ wihb,
       const float* __restrict__ bih, const float* __restrict__ bhh,
       unsigned short* __restrict__ P2)
{
  const int l  = threadIdx.x & 63;
  const int w  = threadIdx.x >> 6;
  const int n0 = blockIdx.x * 128 + (w & 1) * 64;
  const int m0 = blockIdx.y * 128 + (w >> 1) * 64;
  const int lq = l >> 4, lc = l & 15;

  f32x4 acc[4][4];
  #pragma unroll
  for (int a = 0; a < 4; ++a)
    #pragma unroll
    for (int b = 0; b < 4; ++b) acc[a][b] = (f32x4){0.f, 0.f, 0.f, 0.f};

  const uint8_t* eb = (const uint8_t*)embT;
  const uint8_t* wb = (const uint8_t*)wihb;
  #pragma unroll
  for (int ks = 0; ks < 8; ++ks) {
    const int koff = ks * 64 + lq * 16;
    bf16x8 a[4], b[4];
    #pragma unroll
    for (int mt = 0; mt < 4; ++mt) {
      int row = m0 + mt * 16 + lc; if (row >= VOCAB) row = VOCAB - 1;
      a[mt] = *(const bf16x8*)(eb + (size_t)row * 512 + koff);
    }
    #pragma unroll
    for (int nt = 0; nt < 4; ++nt) {
      int g = n0 + nt * 16 + lc;
      b[nt] = *(const bf16x8*)(wb + (size_t)g * 512 + koff);
    }
    #pragma unroll
    for (int mt = 0; mt < 4; ++mt)
      #pragma unroll
      for (int nt = 0; nt < 4; ++nt)
        acc[mt][nt] = __builtin_amdgcn_mfma_f32_16x16x32_bf16(a[mt], b[nt], acc[mt][nt], 0, 0, 0);
  }

  #pragma unroll
  for (int mt = 0; mt < 4; ++mt)
    #pragma unroll
    for (int r = 0; r < 4; ++r) {
      const int vrow = m0 + mt * 16 + lq * 4 + r;
      if (vrow < VOCAB) {
        #pragma unroll
        for (int nt = 0; nt < 4; ++nt) {
          const int gcol = n0 + nt * 16 + lc;
          float v = acc[mt][nt][r] + bih[gcol] + bhh[gcol];
          const int colp = ((gcol & 511) << 2) | (gcol >> 9);  // [j][g] permuted
          P2[(size_t)vrow * 2048 + colp] = f2bf(v);
        }
      }
    }
}

// ------------------------------------------------------------------
// K3: persistent LSTM scan. 256 blocks x 256 threads (4 waves).
// block = (lstm, mg: 32 batch rows, jb: 32 hidden cols). wave = gate.
// W_hh slice (128KB) + h tile (32KB, xor-swizzled, reused as f32 gate
// buffer) = 160KB LDS. h via relaxed agent-scope atomics (MALL).
// Sync: per-block FLAG WORD at 256B stride (no RMW, no line sharing);
// wave-0 lanes poll the 16 peer flags in parallel.
// ------------------------------------------------------------------
#define HL 131072   // LDS offset of h / gate-exchange region

__global__ __launch_bounds__(256, 1) void
k_lstm(const uint8_t* __restrict__ P2, const int* __restrict__ tokT,
       const uint8_t* __restrict__ whh, uint8_t* __restrict__ hbuf,
       unsigned* __restrict__ flags)
{
  __shared__ __align__(16) uint8_t smem[163840];
  const int tid  = threadIdx.x;
  const int l    = tid & 63;
  const int w    = tid >> 6;        // wave = gate index
  const int bid  = blockIdx.x;
  const int jb   = bid & 15;
  const int mg   = (bid >> 4) & 7;
  const int lstm = bid >> 7;
  const int grp  = bid >> 4;        // 0..15, 16 blocks each (lstm, mg)
  const int m0   = mg * 32;
  const int j0   = jb * 32;

  // ---- stage W_hh gate-slice into LDS once, xor-swizzled ----
  // LDS row R = g*32 + jl  <->  W_hh row g*512 + j0 + jl ; 16B chunk c at (c ^ (R&7))
  for (int i = 0; i < 32; ++i) {
    const int G = i * 256 + tid;            // chunk id 0..8191
    const int R = G >> 6, c = G & 63;
    const uint8_t* src = whh + (size_t)((R >> 5) * 512 + j0 + (R & 31)) * 1024 + (size_t)c * 16;
    const uint4 v = *(const uint4*)src;
    *(uint4*)(smem + (size_t)R * 1024 + ((c ^ (R & 7)) * 16)) = v;
  }

  const size_t hslot = (size_t)NBAT * HIDD * 2;   // 262144 B
  const int em   = tid >> 3;        // epilogue batch row 0..31
  const int ecol = tid & 7;         // epilogue col group (4 cols)
  const int an   = l & 31;          // MFMA A-row / B-col (lane&31)
  const int ah   = l >> 5;          // k-half (lane>>5)
  const int Rrow = w * 32 + an;     // B LDS row

  // poll address: lane i watches peer (grp*16 + (i&15))'s flag (256B stride)
  const unsigned* fpoll = flags + (size_t)(grp * 16 + (l & 15)) * 64;
  unsigned* fmine = flags + (size_t)bid * 64;

  float cst[4] = {0.f, 0.f, 0.f, 0.f};
  int tok_next = tokT[(lstm * TSEQ + 0) * NBAT + m0 + em];

  for (int t = 0; t < TSEQ; ++t) {
    const int tok_cur = tok_next;

    // ---- issue xg gather + next-token load FIRST (hides under the poll) ----
    const uint8_t* xsrc = P2 + (size_t)tok_cur * 4096 + (size_t)j0 * 8 + (size_t)ecol * 32;
    const uint4 xq0 = *(const uint4*)(xsrc);
    const uint4 xq1 = *(const uint4*)(xsrc + 16);
    if (t + 1 < TSEQ) tok_next = tokT[(lstm * TSEQ + (t + 1)) * NBAT + m0 + em];

    // ---- wait for all 16 peer blocks to have completed step t-1 ----
    if (t > 0 && w == 0) {
      const unsigned tgt = (unsigned)t;
      int guard = 0;
      for (;;) {
        const unsigned v = __hip_atomic_load(fpoll, __ATOMIC_RELAXED, __HIP_MEMORY_SCOPE_AGENT);
        if (__all((int)(v >= tgt))) break;
        __builtin_amdgcn_s_sleep(1);
        if (++guard > 400000) break;           // fail visible, not hung
      }
    }
    __syncthreads();   // all waves past poll; LDS h region free (epilogue reads done)

    // ---- stage h tile (32 rows x 1KB) via agent-scope atomic loads ----
    {
      const uint8_t* hb = hbuf + (size_t)(lstm * 2 + (t & 1)) * hslot
                        + (size_t)m0 * 1024 + (size_t)tid * 8;
      unsigned long long v[16];
      #pragma unroll
      for (int i = 0; i < 16; ++i)
        v[i] = __hip_atomic_load((const unsigned long long*)(hb + (size_t)i * 2048),
                                 __ATOMIC_RELAXED, __HIP_MEMORY_SCOPE_AGENT);
      #pragma unroll
      for (int i = 0; i < 16; ++i) {
        const int m = i * 2 + (tid >> 7);
        const int c = (tid >> 1) & 63;
        const int half = tid & 1;
        *(unsigned long long*)(smem + HL + (size_t)m * 1024
                               + ((c ^ (m & 7)) * 16) + half * 8) = v[i];
      }
    }
    __syncthreads();   // h LDS ready (W resident since before t-loop)

    // ---- GEMM: gate_w[32x32] = h[32x512] . W_g[32x512]^T (32x32x16 MFMA) ----
    f32x16 acc0{}, acc1{};
    #pragma unroll 8
    for (int ks = 0; ks < 32; ++ks) {
      const int ch = ks * 2 + ah;
      const bf16x8 av = *(const bf16x8*)(smem + HL + (size_t)an * 1024 + ((ch ^ (an & 7)) * 16));
      const bf16x8 bv = *(const bf16x8*)(smem + (size_t)Rrow * 1024 + ((ch ^ (an & 7)) * 16));
      if (ks & 1) acc1 = __builtin_amdgcn_mfma_f32_32x32x16_bf16(av, bv, acc1, 0, 0, 0);
      else        acc0 = __builtin_amdgcn_mfma_f32_32x32x16_bf16(av, bv, acc0, 0, 0, 0);
    }
    __syncthreads();   // A reads done; h region reusable as f32 gate buffer

    {
      float* gb = (float*)(smem + HL);   // gbuf[g][row 0..31][col 0..31] f32
      #pragma unroll
      for (int r = 0; r < 16; ++r) {
        const int row = (r & 3) + 8 * (r >> 2) + 4 * ah;   // 32x32 C/D mapping
        gb[w * 1024 + row * 32 + an] = acc0[r] + acc1[r];
      }
    }
    __syncthreads();   // gate buffer ready

    // ---- epilogue: 4 cells/lane, lane-local nonlinearity, h -> coherence pt ----
    {
      const float* gb = (const float*)(smem + HL);
      const f32x4 pi = *(const f32x4*)(gb + 0 * 1024 + em * 32 + ecol * 4);
      const f32x4 pf = *(const f32x4*)(gb + 1 * 1024 + em * 32 + ecol * 4);
      const f32x4 pg = *(const f32x4*)(gb + 2 * 1024 + em * 32 + ecol * 4);
      const f32x4 po = *(const f32x4*)(gb + 3 * 1024 + em * 32 + ecol * 4);
      unsigned short xsv[16];
      *(uint4*)(xsv) = xq0;
      *(uint4*)(xsv + 8) = xq1;
      unsigned short hv[4];
      #pragma unroll
      for (int k = 0; k < 4; ++k) {
        const float iv = sigf(pi[k] + b2f(xsv[k * 4 + 0]));
        const float fv = sigf(pf[k] + b2f(xsv[k * 4 + 1]));
        const float gv = tanhf_(pg[k] + b2f(xsv[k * 4 + 2]));
        const float ov = sigf(po[k] + b2f(xsv[k * 4 + 3]));
        const float cv = fv * cst[k] + iv * gv;
        cst[k] = cv;
        hv[k] = f2bf(ov * tanhf_(cv));
      }
      unsigned long long hp =
          (unsigned long long)hv[0] | ((unsigned long long)hv[1] << 16) |
          ((unsigned long long)hv[2] << 32) | ((unsigned long long)hv[3] << 48);
      uint8_t* hdst = hbuf + (size_t)(lstm * 2 + ((t + 1) & 1)) * hslot
                    + (size_t)(m0 + em) * 1024 + (size_t)(j0 + ecol * 4) * 2;
      __hip_atomic_store((unsigned long long*)hdst, hp,
                         __ATOMIC_RELAXED, __HIP_MEMORY_SCOPE_AGENT);
    }
    __syncthreads();   // barrier drain (s_waitcnt vmcnt(0)) => h at coherence point

    if (tid == 0 && t + 1 < TSEQ)
      __hip_atomic_store(fmine, (unsigned)(t + 1),
                         __ATOMIC_RELAXED, __HIP_MEMORY_SCOPE_AGENT);
  }
}

// ------------------------------------------------------------------
// K4: h1*h2 -> logits -> softmax. one wave per batch row.
// ------------------------------------------------------------------
__global__ __launch_bounds__(64) void
k_fc(const uint8_t* __restrict__ hbuf, const float* __restrict__ wfc,
     const float* __restrict__ bfc, float* __restrict__ out)
{
  const int n = blockIdx.x, l = threadIdx.x;
  const unsigned short* h1 = (const unsigned short*)(hbuf) + (size_t)n * HIDD;
  const unsigned short* h2 = (const unsigned short*)(hbuf + 2 * (size_t)NBAT * HIDD * 2) + (size_t)n * HIDD;
  float s0 = 0.f, s1 = 0.f;
  for (int j = l; j < HIDD; j += 64) {
    float hv = b2f(h1[j]) * b2f(h2[j]);
    s0 += hv * wfc[j];
    s1 += hv * wfc[HIDD + j];
  }
  #pragma unroll
  for (int off = 32; off > 0; off >>= 1) {
    s0 += __shfl_down(s0, off, 64);
    s1 += __shfl_down(s1, off, 64);
  }
  if (l == 0) {
    s0 += bfc[0]; s1 += bfc[1];
    float m  = fmaxf(s0, s1);
    float e0 = __builtin_amdgcn_exp2f((s0 - m) * 1.4426950408889634f);
    float e1 = __builtin_amdgcn_exp2f((s1 - m) * 1.4426950408889634f);
    float inv = 1.0f / (e0 + e1);
    out[n * 2 + 0] = e0 * inv;
    out[n * 2 + 1] = e1 * inv;
  }
}

// ------------------------------------------------------------------
extern "C" void kernel_launch(void* const* d_in, const int* in_sizes, int n_in,
                              void* d_out, int out_size, void* d_ws, size_t ws_size,
                              hipStream_t stream) {
  (void)in_sizes; (void)n_in; (void)out_size;
  if (ws_size < WS_NEED) return;   // fail visibly rather than scribble OOB

  const int*   tok1 = (const int*)d_in[0];
  const int*   tok2 = (const int*)d_in[1];
  const float* emb  = (const float*)d_in[2];
  const float* wih  = (const float*)d_in[3];
  const float* whh  = (const float*)d_in[4];
  const float* bih  = (const float*)d_in[5];
  const float* bhh  = (const float*)d_in[6];
  const float* wfc  = (const float*)d_in[7];
  const float* bfc  = (const float*)d_in[8];
  float* out = (float*)d_out;

  uint8_t* ws = (uint8_t*)d_ws;
  unsigned short* P2    = (unsigned short*)(ws + O_P2);
  unsigned short* embT  = (unsigned short*)(ws + O_EMBT);
  unsigned short* wihb  = (unsigned short*)(ws + O_WIH);
  unsigned short* whhb  = (unsigned short*)(ws + O_WHH);
  int*            tokT  = (int*)(ws + O_TOKT);
  uint8_t*        hbuf  = ws + O_HBUF;
  unsigned*       flags = (unsigned*)(ws + O_FLAGS);

  k_prep<<<1024, 256, 0, stream>>>(emb, wih, whh, tok1, tok2, embT, wihb, whhb,
                                   tokT, (unsigned*)hbuf);
  k_proj<<<dim3(16, 391), 256, 0, stream>>>(embT, wihb, bih, bhh, P2);
  k_zero<<<64, 256, 0, stream>>>(flags);   // embT dead after k_proj; flags live there

  {
    const uint8_t* p2p = (const uint8_t*)P2;
    const int*     tkp = tokT;
    const uint8_t* whp = (const uint8_t*)whhb;
    uint8_t*       hbp = hbuf;
    unsigned*      flp = flags;
    void* args[5] = {(void*)&p2p, (void*)&tkp, (void*)&whp, (void*)&hbp, (void*)&flp};
    hipError_t e = hipLaunchCooperativeKernel((void*)k_lstm, dim3(256), dim3(256),
                                              args, 0, stream);
    if (e != hipSuccess) {
      (void)hipGetLastError();  // clear; fall back (256 blocks @ 1/CU are co-resident)
      k_lstm<<<256, 256, 0, stream>>>(p2p, tkp, whp, hbp, flp);
    }
  }

  k_fc<<<256, 64, 0, stream>>>(hbuf, wfc, bfc, out);
}